// Round 2
// baseline (180.748 us; speedup 1.0000x reference)
//
#include <hip/hip_runtime.h>

// x: (4, 32, 256, 256) fp32. WINDOW=16, STRIDE=8, EPS=1e-6.
// out[b, l, c, ph, pw] = x[b, c, ho*8+ph, wo*8+pw] + EPS * sum(16x16 patch),
// l = ho*31 + wo, out shape (4, 961, 32, 16, 16)  (~126 MB writes, 33.5 MB input).
//
// v3: DECOUPLE reduction from streaming (round-1 lesson: any dep chain between
// load and store kills store issue rate; the poison fill proves 6.9 TB/s is
// reachable with dep-free stores on this buffer).
//   pass 1: patch sums -> workspace (reads 33.5 MB, writes 0.5 MB, ~10 us)
//   pass 2: pure streamer, out = x_gather + eps*psum. Per thread: independent
//           f4 load + LDS scalar + nontemporal f4 store, x8 unrolled, no
//           barriers in the loop, no shuffles. One block per (b,l) writes
//           32 KB contiguous. ~25 us at write BW.

#define BB   4
#define CC   32
#define HH   256
#define WW   256
#define STR  8
#define HOC  31
#define WOC  31
#define LL   (HOC * WOC)   // 961
#define EPSF 1e-6f

typedef float f4 __attribute__((ext_vector_type(4)));

// ---------------- pass 1: patch sums ----------------
// grid (CC, HOC, BB), 256 thr. psum[(b*LL + ho*31 + wo)*CC + c] = 16x16 sum.
// No strip staging -- only the sums. LDS = 2 KB.
__global__ __launch_bounds__(256) void
patch_sums(const float* __restrict__ x, float* __restrict__ psum) {
    __shared__ float cs[16 * 32];   // [row][chunk-of-8]
    const int tid = threadIdx.x;
    const int c   = blockIdx.x;
    const int ho  = blockIdx.y;
    const int b   = blockIdx.z;
    const float* src = x + ((size_t)(b * CC + c) * HH + (size_t)(ho * STR)) * WW;

#pragma unroll
    for (int it = 0; it < 4; ++it) {
        const int g = (it * 256 + tid) * 4;       // float idx in 16x256 strip
        const f4 v  = *(const f4*)(src + g);
        float s4 = v.x + v.y + v.z + v.w;
        s4 += __shfl_xor(s4, 1, 64);              // pair (t, t^1) = 8-col chunk
        if ((tid & 1) == 0)
            cs[g >> 3] = s4;                      // = row*32 + col/8
    }
    __syncthreads();

    // patch cols [8wo, 8wo+16) = chunks wo and wo+1  (fixed: was 2wo, 2wo+1)
    if (tid < WOC) {
        float s = 0.f;
#pragma unroll
        for (int r = 0; r < 16; ++r)
            s += cs[r * 32 + tid] + cs[r * 32 + tid + 1];
        psum[((size_t)b * LL + (size_t)ho * WOC + tid) * CC + c] = s;
    }
}

// ---------------- pass 2: streaming emit ----------------
// grid (LL, BB), 256 thr. Block (l, b) writes out[b][l][0..31][..] = 32 KB
// CONTIGUOUS. Iter k: wave w emits patch c = 4k+w (uniform psum per wave).
__global__ __launch_bounds__(256) void
emit_patches(const float* __restrict__ x, const float* __restrict__ psum,
             float* __restrict__ out) {
    __shared__ float eps_s[CC];
    const int tid = threadIdx.x;
    const int l   = blockIdx.x;
    const int b   = blockIdx.y;
    const int ho  = l / WOC;
    const int wo  = l - ho * WOC;

    if (tid < CC)
        eps_s[tid] = EPSF * psum[((size_t)b * LL + l) * CC + tid];
    __syncthreads();

    const int q4 = tid & 63;          // float4 slot within a 256-float patch
    const int r  = q4 >> 2;           // patch row 0..15
    const int qc = (q4 & 3) * 4;      // patch col offset (16B aligned)
    const int w0 = tid >> 6;          // wave 0..3

    const float* xb = x + ((size_t)(b * CC) * HH + (size_t)(ho * STR + r)) * WW
                        + (size_t)(wo * STR + qc);
    float* ob = out + ((size_t)b * LL + l) * (CC * 256) + (size_t)(tid * 4);

#pragma unroll
    for (int k = 0; k < 8; ++k) {                 // 8 independent load+store
        const int c = k * 4 + w0;
        const f4 v  = *(const f4*)(xb + (size_t)c * (HH * WW));
        const f4 o  = v + eps_s[c];
        __builtin_nontemporal_store(o, (f4*)(ob + k * 1024));
    }
}

// ---------------- fallback (workspace too small): fused strip ----------------
#define PITCH 272
__global__ __launch_bounds__(256) void
extract_patches_strip(const float* __restrict__ x, float* __restrict__ out) {
    __shared__ float strip[16 * PITCH];
    __shared__ float cs[16 * 32];
    __shared__ float epsP[32];
    const int tid = threadIdx.x;
    const int c = blockIdx.x, ho = blockIdx.y, b = blockIdx.z;
    const float* src = x + ((size_t)(b * CC + c) * HH + (size_t)(ho * STR)) * WW;
#pragma unroll
    for (int it = 0; it < 4; ++it) {
        const int g = (it * 256 + tid) * 4;
        const f4 v = *(const f4*)(src + g);
        const int row = g >> 8, col = g & 255;
        *(f4*)(&strip[row * PITCH + col]) = v;
        float s4 = v.x + v.y + v.z + v.w;
        s4 += __shfl_xor(s4, 1, 64);
        if ((tid & 1) == 0) cs[g >> 3] = s4;
    }
    __syncthreads();
    if (tid < WOC) {
        float s = 0.f;
#pragma unroll
        for (int r = 0; r < 16; ++r)
            s += cs[r * 32 + tid] + cs[r * 32 + tid + 1];
        epsP[tid] = EPSF * s;
    }
    __syncthreads();
    const int wave = tid >> 6, lane = tid & 63;
    const int prow = lane >> 2, pcol4 = (lane & 3) * 4;
    float* dstbase = out + (((size_t)b * LL + (size_t)ho * WOC) * CC + c) * 256
                   + (size_t)(lane * 4);
#pragma unroll
    for (int p = 0; p < 8; ++p) {
        const int wo = p * 4 + wave;
        if (wo < WOC) {
            const f4 v = *(const f4*)(&strip[prow * PITCH + wo * STR + pcol4]);
            const float e = epsP[wo];
            __builtin_nontemporal_store(v + e, (f4*)(dstbase + ((size_t)wo << 13)));
        }
    }
}

extern "C" void kernel_launch(void* const* d_in, const int* in_sizes, int n_in,
                              void* d_out, int out_size, void* d_ws, size_t ws_size,
                              hipStream_t stream) {
    const float* x = (const float*)d_in[0];
    float* out = (float*)d_out;
    const size_t psum_bytes = (size_t)BB * LL * CC * sizeof(float);  // 492 KB

    if (ws_size >= psum_bytes && d_ws != nullptr) {
        float* psum = (float*)d_ws;
        patch_sums<<<dim3(CC, HOC, BB), dim3(256), 0, stream>>>(x, psum);
        emit_patches<<<dim3(LL, BB), dim3(256), 0, stream>>>(x, psum, out);
    } else {
        extract_patches_strip<<<dim3(CC, HOC, BB), dim3(256), 0, stream>>>(x, out);
    }
}

// Round 4
// 156.610 us; speedup vs baseline: 1.1541x; 1.1541x over previous
//
#include <hip/hip_runtime.h>

// x: (4, 32, 256, 256) fp32. WINDOW=16, STRIDE=8, EPS=1e-6.
// out[b, l, c, ph, pw] = x[b, c, ho*8+ph, wo*8+pw] + EPS * sum(16x16 patch),
// l = ho*31 + wo, out shape (4, 961, 32, 16, 16)  (~126 MB write, 33.5 MB in).
//
// v4 lessons applied:
//  r1: any long shuffle chain between load and store kills issue rate -> use
//      only a 3-step shfl_xor within 8-lane groups.
//  r2: extra dispatches + psum round-trip cost more than they save -> single
//      fused dispatch.
//  r1+r2: nontemporal stores regressed twice; the fast poison fill uses plain
//      cached stores -> PLAIN stores.
//  r0: LDS staging + barriers + a 31-thread serial phase is beatable ->
//      zero LDS, zero barriers, full register residency.
//
// Structure: one block (256 thr) per (b, l). Thread t owns 32 floats of
// channel c = t>>3 (2 interleaved patch rows): loads them as 8 independent
// f4s, 8-lane-group reduction (shfl_xor 1,2,4) gives the 16x16 patch sum,
// stores the same regs + eps*s. Per store instruction each 8-lane group
// writes one full 128 B line; block writes 32 KB contiguous. No cross-wave
// coupling anywhere. Bijective XCD swizzle clusters consecutive l per XCD
// so the 3.75x-redundant x reads stay L2-hot (512 KB band per (b,ho)).
//
// (Round-3 bench was an infra failure -- "container failed twice" -- so this
// is a byte-identical resubmit for a clean measurement of the v4 theory.)

#define BB   4
#define CC   32
#define HH   256
#define WW   256
#define STR  8
#define HOC  31
#define WOC  31
#define LL   (HOC * WOC)   // 961
#define EPSF 1e-6f
#define NXCD 8

typedef float f4 __attribute__((ext_vector_type(4)));

__global__ __launch_bounds__(256) void
extract_patches_fused(const float* __restrict__ x, float* __restrict__ out) {
    // ---- bijective XCD-chunked swizzle over nwg = 3844 (not %8==0) ----
    const int nwg  = LL * BB;                       // 3844
    const int q    = nwg / NXCD;                    // 480
    const int rr   = nwg % NXCD;                    // 4
    const int hwid = blockIdx.x + LL * blockIdx.y;
    const int xcd  = hwid & (NXCD - 1);
    const int idx  = hwid >> 3;
    const int swz  = (xcd < rr ? xcd * (q + 1)
                               : rr * (q + 1) + (xcd - rr) * q) + idx;
    const int l = swz % LL;
    const int b = swz / LL;

    const int ho = l / WOC;
    const int wo = l - ho * WOC;

    const int t   = threadIdx.x;
    const int c   = t >> 3;             // channel 0..31 (8 lanes per channel)
    const int sub = t & 7;
    const int r0  = sub >> 2;           // row parity: 0 or 1
    const int col = (sub & 3) * 4;      // col quad: 0,4,8,12

    // ---- load: 8 independent f4s = rows {r0, 2+r0, .., 14+r0}, cols [col,col+4) ----
    const float* px = x + ((size_t)(b * CC + c) * HH + (size_t)(ho * STR)) * WW
                        + (size_t)(wo * STR) + col;
    f4 v[8];
#pragma unroll
    for (int k = 0; k < 8; ++k)
        v[k] = *(const f4*)(px + (size_t)(2 * k + r0) * WW);

    // ---- patch sum: per-thread 32-float sum + 3-step 8-lane-group butterfly ----
    float s = 0.f;
#pragma unroll
    for (int k = 0; k < 8; ++k)
        s += (v[k].x + v[k].y) + (v[k].z + v[k].w);
    s += __shfl_xor(s, 1, 64);
    s += __shfl_xor(s, 2, 64);
    s += __shfl_xor(s, 4, 64);          // all 8 lanes of channel c hold full sum
    const float e = EPSF * s;

    // ---- store: float offset k*32 + sub*4 == row*16 + col (verified identity);
    //      per instruction each 8-lane group writes one full 128 B line ----
    float* po = out + ((size_t)b * LL + l) * (CC * 256)
                    + (size_t)c * 256 + (size_t)(sub * 4);
#pragma unroll
    for (int k = 0; k < 8; ++k)
        *(f4*)(po + k * 32) = v[k] + e;
}

extern "C" void kernel_launch(void* const* d_in, const int* in_sizes, int n_in,
                              void* d_out, int out_size, void* d_ws, size_t ws_size,
                              hipStream_t stream) {
    const float* x = (const float*)d_in[0];
    float* out = (float*)d_out;

    dim3 grid(LL, BB);   // (961, 4) = 3844 blocks, one per output patch-group
    dim3 block(256);
    extract_patches_fused<<<grid, block, 0, stream>>>(x, out);
}

// Round 6
// 147.459 us; speedup vs baseline: 1.2258x; 1.0621x over previous
//
#include <hip/hip_runtime.h>

// x: (4, 32, 256, 256) fp32. WINDOW=16, STRIDE=8, EPS=1e-6.
// out[b, l, c, ph, pw] = x[b, c, ho*8+ph, wo*8+pw] + EPS * sum(16x16 patch),
// l = ho*31 + wo, out shape (4, 961, 32, 16, 16)  (~126 MB write, 33.5 MB in).
//
// v5 = round-0 champion structure (strip staging) + targeted polish.
// Cross-round evidence: read-once coalesced staging beats every alternative
// (flat gather +21 us, two-pass +31 us, register gather +7.5 us: scattered
// 64 B reads cost more than LDS+barriers). Plain stores (NT regressed 2x).
// Polish over r0:
//  - psum phase: 124 threads (4-lane shfl groups), was 31 serial threads.
//  - emit: batch all 8 ds_read_b128 + epsP into regs first (independent,
//    pipelined under lgkmcnt), then a pure store burst -- no ds_read->store
//    dependency interleave.
//  - fixed r0's psum chunk indexing (2wo -> wo,wo+1).
//
// (Round-5 bench was an infra failure -- GPU acquisition timeout -- so this
// is a byte-identical resubmit for a clean measurement of the v5 theory.)

#define BB   4
#define CC   32
#define HH   256
#define WW   256
#define STR  8
#define HOC  31
#define WOC  31
#define LL   (HOC * WOC)   // 961
#define EPSF 1e-6f
#define PITCH 272          // 256+16: rows alternate bank halves, emit conflict-free

typedef float f4 __attribute__((ext_vector_type(4)));

__global__ __launch_bounds__(256) void
extract_patches_strip(const float* __restrict__ x, float* __restrict__ out) {
    __shared__ float strip[16 * PITCH];   // 17408 B
    __shared__ float cs[16 * 32];         // [row][8-col chunk] sums, 2 KB
    __shared__ float epsP[32];            // eps * patch sum per wo (31 used)

    const int tid = threadIdx.x;
    const int c   = blockIdx.x;   // 0..31
    const int ho  = blockIdx.y;   // 0..30
    const int b   = blockIdx.z;   // 0..3

    const float* src = x + ((size_t)(b * CC + c) * HH + (size_t)(ho * STR)) * WW;

    // ---- stage 16 KB strip + fold 8-col chunk sums in flight ----
#pragma unroll
    for (int it = 0; it < 4; ++it) {
        const int g   = (it * 256 + tid) * 4;   // float idx in 16x256 strip
        const f4 v    = *(const f4*)(src + g);
        const int row = g >> 8;
        const int col = g & 255;
        *(f4*)(&strip[row * PITCH + col]) = v;
        float s4 = (v.x + v.y) + (v.z + v.w);
        s4 += __shfl_xor(s4, 1, 64);            // pair (t, t^1) = one 8-chunk
        if ((tid & 1) == 0)
            cs[g >> 3] = s4;                    // chunk idx = row*32 + col/8
    }
    __syncthreads();

    // ---- patch sums, 124 threads: wo = t>>2, row-group rg = t&3 ----
    if (tid < 4 * WOC) {
        const int wo = tid >> 2;
        const int rg = tid & 3;
        float s = 0.f;
#pragma unroll
        for (int r = 4 * rg; r < 4 * rg + 4; ++r)
            s += cs[r * 32 + wo] + cs[r * 32 + wo + 1];   // cols [8wo, 8wo+16)
        s += __shfl_xor(s, 1, 64);              // 4-lane group reduce
        s += __shfl_xor(s, 2, 64);              // (groups never straddle waves)
        if (rg == 0)
            epsP[wo] = EPSF * s;
    }
    __syncthreads();

    // ---- emit 31 patches: wave w -> wo = 4p + w ----
    const int wave  = tid >> 6;
    const int lane  = tid & 63;
    const int prow  = lane >> 2;        // patch row 0..15
    const int pcol4 = (lane & 3) * 4;   // patch col quad
    float* dstbase = out
        + (((size_t)b * LL + (size_t)ho * WOC) * CC + c) * 256
        + (size_t)(lane * 4);

    // phase 1: all LDS reads in flight (independent), epsP hoisted to regs
    f4    vv[8];
    float ee[8];
#pragma unroll
    for (int p = 0; p < 8; ++p) {
        const int wo = p * 4 + wave;
        const int w2 = (wo < WOC) ? wo : 0;     // wave 3, p=7: dummy (unstored)
        vv[p] = *(const f4*)(&strip[prow * PITCH + w2 * STR + pcol4]);
        ee[p] = epsP[w2];
    }
    // phase 2: pure store burst, 1 KB contiguous per wave-instruction
#pragma unroll
    for (int p = 0; p < 8; ++p) {
        const int wo = p * 4 + wave;
        if (wo < WOC)
            *(f4*)(dstbase + ((size_t)wo << 13)) = vv[p] + ee[p];
    }
}

extern "C" void kernel_launch(void* const* d_in, const int* in_sizes, int n_in,
                              void* d_out, int out_size, void* d_ws, size_t ws_size,
                              hipStream_t stream) {
    const float* x = (const float*)d_in[0];
    float* out = (float*)d_out;

    dim3 grid(CC, HOC, BB);   // (32, 31, 4) = 3968 blocks
    dim3 block(256);
    extract_patches_strip<<<grid, block, 0, stream>>>(x, out);
}